// Round 16
// baseline (241.882 us; speedup 1.0000x reference)
//
#include <hip/hip_runtime.h>
#include <math.h>

#define NE 64
#define NTOK 16384
#define DD 4096
#define TOPK 2
#define BLOCK 512            // 8 waves = 4 token-tiles x 2 expert-pairs
#define TOKPB 64
#define NSTEP (DD / 32)      // 128 K-steps of 32
#define LGSTR 68             // logit plane row stride (dwords)

// ws layout (bytes): [0,512) loss partials (2x64 f32); [512, 512+512K) gwh;
// [512+512K, 512+1M) gwl. Pre-split mode requires ws_size >= WS_NEED.
#define WSH_OFF 512
#define WSL_OFF (WSH_OFF + NE * DD * 2)
#define WS_NEED (WSL_OFF + NE * DD * 2)

using half8 = __attribute__((ext_vector_type(8))) _Float16;
using f32x4 = __attribute__((ext_vector_type(4))) float;

// Dekker split: v*64 -> hi fp16 + exact-residual lo fp16. Scale 64 (pow2)
// keeps lo out of fp16 subnormals for x~N(0,1), w~N(0,0.01); accumulator is
// 4096*logit, unscaled exactly by 2^-12 in the epilogue. (R15-verified.)
__device__ __forceinline__ void split8(const f32x4 a, const f32x4 b,
                                       half8& hi, half8& lo) {
#pragma unroll
  for (int i = 0; i < 4; ++i) {
    const float v = a[i] * 64.0f;
    const _Float16 h = (_Float16)v;
    hi[i] = h;
    lo[i] = (_Float16)(v - (float)h);
  }
#pragma unroll
  for (int i = 0; i < 4; ++i) {
    const float v = b[i] * 64.0f;
    const _Float16 h = (_Float16)v;
    hi[4 + i] = h;
    lo[4 + i] = (_Float16)(v - (float)h);
  }
}

// one-shot gate_w split: 64x4096 floats -> gwh/gwl (half, row-major)
__global__ void wsplit_kernel(const float* __restrict__ gw,
                              _Float16* __restrict__ gh,
                              _Float16* __restrict__ gl) {
  const int i = (blockIdx.x * 256 + threadIdx.x) * 8;
  const f32x4 a = *(const f32x4*)(gw + i);
  const f32x4 b = *(const f32x4*)(gw + i + 4);
  half8 h, l;
  split8(a, b, h, l);
  *(half8*)(gh + i) = h;
  *(half8*)(gl + i) = l;
}

template <bool PRE>
__global__ __launch_bounds__(BLOCK) void router_kernel(
    const float* __restrict__ x, const float* __restrict__ gw,
    const _Float16* __restrict__ gwh, const _Float16* __restrict__ gwl,
    float* __restrict__ out, float* __restrict__ ws) {
  __shared__ __align__(16) float pl[TOKPB * LGSTR];  // 17.4 KB logit plane

  const int tid = threadIdx.x;
  const int lane = tid & 63;
  const int wid = __builtin_amdgcn_readfirstlane(tid >> 6);
  const int mi = wid & 3;          // token tile (16 rows)
  const int np = wid >> 2;         // expert pair: cols np*32 .. np*32+31
  const int tok0 = blockIdx.x * TOKPB;
  const int r = lane & 15;         // row-in-tile (A) / col-in-tile (B)
  const int kg = (lane >> 4) * 8;  // per-lane k-group base within a step

  // A: x[tok0+mi*16+r][kg..kg+8) per lane; k-slot bijection cancels A vs B.
  const float* xp = x + (size_t)(tok0 + mi * 16 + r) * DD + kg;
  // B (pre-split halves)
  const _Float16* bh0 = gwh + (size_t)(np * 32 + r) * DD + kg;
  const _Float16* bh1 = bh0 + (size_t)16 * DD;
  const _Float16* bl0 = gwl + (size_t)(np * 32 + r) * DD + kg;
  const _Float16* bl1 = bl0 + (size_t)16 * DD;
  // B (raw, fallback)
  const float* b0p = gw + (size_t)(np * 32 + r) * DD + kg;
  const float* b1p = b0p + (size_t)16 * DD;

  f32x4 acc0 = {0.f, 0.f, 0.f, 0.f};
  f32x4 acc1 = {0.f, 0.f, 0.f, 0.f};

  // x pipeline: 4 steps deep (reload-in-place after consumption -> distance 4)
  f32x4 xa[4], xb[4];
#pragma unroll
  for (int j = 0; j < 4; ++j) {
    xa[j] = *(const f32x4*)(xp + j * 32);
    xb[j] = *(const f32x4*)(xp + j * 32 + 4);
  }
  // B pipeline: 2 banks (distance 2)
  half8 B0h[2], B0l[2], B1h[2], B1l[2];
  f32x4 rb0a[2], rb0b[2], rb1a[2], rb1b[2];
#pragma unroll
  for (int j = 0; j < 2; ++j) {
    if constexpr (PRE) {
      B0h[j] = *(const half8*)(bh0 + j * 32);
      B0l[j] = *(const half8*)(bl0 + j * 32);
      B1h[j] = *(const half8*)(bh1 + j * 32);
      B1l[j] = *(const half8*)(bl1 + j * 32);
    } else {
      rb0a[j] = *(const f32x4*)(b0p + j * 32);
      rb0b[j] = *(const f32x4*)(b0p + j * 32 + 4);
      rb1a[j] = *(const f32x4*)(b1p + j * 32);
      rb1b[j] = *(const f32x4*)(b1p + j * 32 + 4);
    }
  }

#define SUBSTEP(ST, J, XRELOAD, BRELOAD)                                    \
  do {                                                                      \
    half8 Ah, Al;                                                           \
    split8(xa[J], xb[J], Ah, Al);                                           \
    if (XRELOAD) { /* reload same regs for step ST+4 */                     \
      xa[J] = *(const f32x4*)(xp + (ST + 4) * 32);                          \
      xb[J] = *(const f32x4*)(xp + (ST + 4) * 32 + 4);                      \
    }                                                                       \
    half8 h0, l0, h1, l1;                                                   \
    if constexpr (PRE) {                                                    \
      h0 = B0h[(J) & 1]; l0 = B0l[(J) & 1];                                 \
      h1 = B1h[(J) & 1]; l1 = B1l[(J) & 1];                                 \
      if (BRELOAD) {                                                        \
        B0h[(J) & 1] = *(const half8*)(bh0 + (ST + 2) * 32);                \
        B0l[(J) & 1] = *(const half8*)(bl0 + (ST + 2) * 32);                \
        B1h[(J) & 1] = *(const half8*)(bh1 + (ST + 2) * 32);                \
        B1l[(J) & 1] = *(const half8*)(bl1 + (ST + 2) * 32);                \
      }                                                                     \
    } else {                                                                \
      split8(rb0a[(J) & 1], rb0b[(J) & 1], h0, l0);                         \
      split8(rb1a[(J) & 1], rb1b[(J) & 1], h1, l1);                         \
      if (BRELOAD) {                                                        \
        rb0a[(J) & 1] = *(const f32x4*)(b0p + (ST + 2) * 32);               \
        rb0b[(J) & 1] = *(const f32x4*)(b0p + (ST + 2) * 32 + 4);           \
        rb1a[(J) & 1] = *(const f32x4*)(b1p + (ST + 2) * 32);               \
        rb1b[(J) & 1] = *(const f32x4*)(b1p + (ST + 2) * 32 + 4);           \
      }                                                                     \
    }                                                                       \
    acc0 = __builtin_amdgcn_mfma_f32_16x16x32_f16(Al, h0, acc0, 0, 0, 0);   \
    acc0 = __builtin_amdgcn_mfma_f32_16x16x32_f16(Ah, l0, acc0, 0, 0, 0);   \
    acc0 = __builtin_amdgcn_mfma_f32_16x16x32_f16(Ah, h0, acc0, 0, 0, 0);   \
    acc1 = __builtin_amdgcn_mfma_f32_16x16x32_f16(Al, h1, acc1, 0, 0, 0);   \
    acc1 = __builtin_amdgcn_mfma_f32_16x16x32_f16(Ah, l1, acc1, 0, 0, 0);   \
    acc1 = __builtin_amdgcn_mfma_f32_16x16x32_f16(Ah, h1, acc1, 0, 0, 0);   \
  } while (0)

  // main: 31 full iterations (all reloads in-bounds: st+4 <= 127 ✓)
#pragma unroll 1
  for (int i = 0; i < NSTEP / 4 - 1; ++i) {
    const int st = i * 4;
    SUBSTEP(st + 0, 0, 1, 1);
    SUBSTEP(st + 1, 1, 1, 1);
    SUBSTEP(st + 2, 2, 1, 1);
    SUBSTEP(st + 3, 3, 1, 1);
  }
  {  // peeled last iteration: no x reload; B reload only for j<2
    const int st = NSTEP - 4;
    SUBSTEP(st + 0, 0, 0, 1);
    SUBSTEP(st + 1, 1, 0, 1);
    SUBSTEP(st + 2, 2, 0, 0);
    SUBSTEP(st + 3, 3, 0, 0);
  }
#undef SUBSTEP

  // C layout (m89-verified): col = lane&15 (expert), row = (lane>>4)*4 + i
  {
    const int trow = (lane >> 4) * 4;
#pragma unroll
    for (int i = 0; i < 4; ++i) {
      pl[(mi * 16 + trow + i) * LGSTR + np * 32 + r] =
          acc0[i] * 2.44140625e-4f;  // 2^-12 unscale (exact)
      pl[(mi * 16 + trow + i) * LGSTR + np * 32 + 16 + r] =
          acc1[i] * 2.44140625e-4f;
    }
  }
  __syncthreads();

  // epilogue: wave wid -> tokens wid*8..+7; lane == expert
  float psum_local = 0.f, cnt_local = 0.f;
  float* out_v = out;                // (NTOK, 2) top-k vals
  float* out_i = out + NTOK * TOPK;  // (NTOK, 2) top-k idx as float
#pragma unroll 1
  for (int ii = 0; ii < 8; ++ii) {
    const int t = wid * 8 + ii;
    float v = pl[t * LGSTR + lane];
    float m = v;
#pragma unroll
    for (int sh = 32; sh > 0; sh >>= 1) m = fmaxf(m, __shfl_xor(m, sh, 64));
    float ex = expf(v - m);
    float ssum = ex;
#pragma unroll
    for (int sh = 32; sh > 0; sh >>= 1) ssum += __shfl_xor(ssum, sh, 64);
    float p = ex / ssum;
    psum_local += p;

    float v1 = p; int i1 = lane;  // top-1, ties -> lowest index
#pragma unroll
    for (int sh = 32; sh > 0; sh >>= 1) {
      float ov = __shfl_xor(v1, sh, 64);
      int oi = __shfl_xor(i1, sh, 64);
      if (ov > v1 || (ov == v1 && oi < i1)) { v1 = ov; i1 = oi; }
    }
    float v2 = (lane == i1) ? -INFINITY : p; int i2 = lane;  // top-2
#pragma unroll
    for (int sh = 32; sh > 0; sh >>= 1) {
      float ov = __shfl_xor(v2, sh, 64);
      int oi = __shfl_xor(i2, sh, 64);
      if (ov > v2 || (ov == v2 && oi < i2)) { v2 = ov; i2 = oi; }
    }
    cnt_local += (lane == i1 ? 1.f : 0.f) + (lane == i2 ? 1.f : 0.f);
    if (lane == 0) {
      const int tg = tok0 + t;
      out_v[tg * 2 + 0] = v1;
      out_v[tg * 2 + 1] = v2;
      out_i[tg * 2 + 0] = (float)i1;
      out_i[tg * 2 + 1] = (float)i2;
    }
  }
  // loss partials: ws[0:64] = pick counts, ws[64:128] = prob sums
  atomicAdd(ws + lane, cnt_local);
  atomicAdd(ws + NE + lane, psum_local);
}

__global__ void loss_kernel(const float* __restrict__ ws,
                            float* __restrict__ out) {
  const int lane = threadIdx.x & 63;
  float f = ws[lane] * (1.f / (float)(NTOK * TOPK));
  float p = ws[NE + lane] * (1.f / (float)NTOK);
  float v = f * p;  // loss = E * mean_i(f_i p_i) = sum_i f_i p_i
#pragma unroll
  for (int sh = 32; sh > 0; sh >>= 1) v += __shfl_xor(v, sh, 64);
  if (lane == 0) out[NTOK * TOPK * 2] = v;
}

extern "C" void kernel_launch(void* const* d_in, const int* in_sizes, int n_in,
                              void* d_out, int out_size, void* d_ws,
                              size_t ws_size, hipStream_t stream) {
  const float* x = (const float*)d_in[0];
  const float* gw = (const float*)d_in[1];
  float* out = (float*)d_out;
  float* ws = (float*)d_ws;

  hipMemsetAsync(d_ws, 0, 512, stream);
  if (ws_size >= (size_t)WS_NEED) {
    _Float16* gh = (_Float16*)((char*)d_ws + WSH_OFF);
    _Float16* gl = (_Float16*)((char*)d_ws + WSL_OFF);
    wsplit_kernel<<<NE * DD / (256 * 8), 256, 0, stream>>>(gw, gh, gl);
    router_kernel<true><<<NTOK / TOKPB, BLOCK, 0, stream>>>(x, gw, gh, gl,
                                                            out, ws);
  } else {
    router_kernel<false><<<NTOK / TOKPB, BLOCK, 0, stream>>>(
        x, gw, nullptr, nullptr, out, ws);
  }
  loss_kernel<<<1, 64, 0, stream>>>(ws, out);
}